// Round 9
// baseline (94.468 us; speedup 1.0000x reference)
//
#include <hip/hip_runtime.h>
#include <hip/hip_bf16.h>
#include <stdint.h>

// Problem constants: N=4096, T=16, D=700 (pad 704), C=128, NC=20
// Output layout (f32): out0 [4096,20] | features [16,4096,128] | attended [16,4096,128]

typedef __attribute__((ext_vector_type(8))) _Float16 half8;  // f16x8 MFMA frag
typedef __attribute__((ext_vector_type(4))) float f32x4;
typedef unsigned long long u64;

#define MFMA16F(a, b, c) __builtin_amdgcn_mfma_f32_16x16x32_f16(a, b, c, 0, 0, 0)

__device__ inline void gload16(const void* g, void* l) {
  __builtin_amdgcn_global_load_lds(
      (const __attribute__((address_space(1))) uint32_t*)g,
      (__attribute__((address_space(3))) uint32_t*)l, 16, 0, 0);
}

// ---------------------------------------------------------------------------
// f16 2-plane split with subnormal-avoiding scales:
//   a = h*2^-4 + l*2^-15 + ra,  |ra| <= 2^-24|a|   (RNE both planes)
// ---------------------------------------------------------------------------
__device__ inline void splitf16(float4 q0, float4 q1, half8& hh, half8& ll) {
  float f[8] = {q0.x, q0.y, q0.z, q0.w, q1.x, q1.y, q1.z, q1.w};
  _Float16 H[8], L[8];
#pragma unroll
  for (int j = 0; j < 8; ++j) {
    _Float16 h1 = (_Float16)(f[j] * 16.0f);          // RNE
    float r = fmaf((float)h1, -0.0625f, f[j]);       // exact residual
    L[j] = (_Float16)(r * 32768.0f);                 // 2^15, RNE
    H[j] = h1;
  }
  __builtin_memcpy(&hh, H, 16);
  __builtin_memcpy(&ll, L, 16);
}

// ---------------------------------------------------------------------------
// Prep: transpose WrT/W2T/WpT + split W_in into 2 f16 planes (k-pad 704)
//   b = p1*2^-8 + p2*2^-19 + rb, |rb| <= 2^-24|b|
// ---------------------------------------------------------------------------
__global__ void k_prep(const float* __restrict__ Wr, const float* __restrict__ W2,
                       const float* __restrict__ Wp, const float* __restrict__ Win,
                       float* __restrict__ WrT, float* __restrict__ W2T,
                       float* __restrict__ WpT, ushort* __restrict__ F2) {
  int idx = blockIdx.x * blockDim.x + threadIdx.x;
  if (idx < 3 * 16384) {
    int sel = idx >> 14;
    int r = idx & 16383;
    int j = r >> 7, c = r & 127;
    const float* src = (sel == 0) ? Wr : (sel == 1) ? W2 : Wp;
    float* dst = (sel == 0) ? WrT : (sel == 1) ? W2T : WpT;
    dst[r] = src[c * 128 + j];
  } else {
    int i2 = idx - 49152;
    if (i2 >= 128 * 704) return;
    int c = i2 / 704, d = i2 - c * 704;
    float w = (d < 700) ? Win[c * 700 + d] : 0.f;
    _Float16 b1 = (_Float16)(w * 256.0f);            // RNE, scale 2^8
    float r = fmaf((float)b1, -0.00390625f, w);      // exact residual
    _Float16 b2 = (_Float16)(r * 524288.0f);         // scale 2^19, RNE
    ushort u1, u2;
    __builtin_memcpy(&u1, &b1, 2);
    __builtin_memcpy(&u2, &b2, 2);
    F2[i2] = u1;
    F2[90112 + i2] = u2;
  }
}

// ---------------------------------------------------------------------------
// Fused GEMM + scan. m-row order m = n*16+t: block owns 8 complete samples.
// GEMM (R7 structure): f16 2-plane 3-product MFMA, 128x128 tile, BK=32,
// 512 threads, wave grid 2(row-64)x4(col-32), dbuf 64KB -> 2 blocks/CU.
// Epilogue: acc -> LDS [64][132] in 2 chunks of 4 samples (wr==chunk waves),
// then 512 threads = 4 samples x 128 ch run LIF1+2, attention, attended,
// LIF3, and the 20-class projection straight from LDS. XW never hits HBM.
// ---------------------------------------------------------------------------
__global__ __launch_bounds__(512, 4) void k_gemm_scan(
    const float* __restrict__ x, const ushort* __restrict__ F2,
    const float* __restrict__ b_in, const float* __restrict__ b_rec,
    const float* __restrict__ WrT, const float* __restrict__ W2T,
    const float* __restrict__ b2, const float* __restrict__ WpT,
    const float* __restrict__ b_p, const float* __restrict__ W_out,
    const float* __restrict__ b_out, const float* __restrict__ k_t,
    const float* __restrict__ k_c, float* __restrict__ features,
    float* __restrict__ attended, float* __restrict__ out0) {
  __shared__ __align__(16) char lds[65536];  // GEMM: 2x(A 16K f32 | B 16K f16x2)
  // Scan overlay (aliases dead staging):
  //   XWs   f32[64][132]  @ 0      (33792 B)
  //   smask u64[4][2]     @ 33792
  //   fmask u64[4][16][2] @ 33856
  //   ta    f32[4][16]    @ 34880
  //   m0p   f32[4][130]   @ 35136
  //   ca    f32[4][128]   @ 37216
  //   g     f32[4][128]   @ 39264  (end 41312)

  const int tid = threadIdx.x;
  const int w = tid >> 6;      // 0..7
  const int l = tid & 63;
  const int blk = blockIdx.x;
  const int wr = w >> 2;       // 0..1  (row group of 64)
  const int wc = w & 3;        // 0..3  (col group of 32)

  // --- A staging: rows m = blk*128 + r are contiguous in x (m*700). ---
  const int jA = (((l & 7) ^ (l >> 3)) * 4);  // chunk-XOR swizzled source k-off
  int arow[2];
#pragma unroll
  for (int i = 0; i < 2; ++i)
    arow[i] = (blk * 128 + (w * 2 + i) * 8 + (l >> 3)) * 700;
  // --- B staging: 2 planes x 8 col-groups, wave does 2. ---
  const ushort* bsrc[2];
  int bdst[2];
#pragma unroll
  for (int i = 0; i < 2; ++i) {
    int idx = w * 2 + i;
    int plane = idx >> 3, cg = idx & 7;
    int col = cg * 16 + (l >> 2);
    bsrc[i] = F2 + plane * 90112 + col * 704 + (((l & 3) ^ ((l >> 3) & 3)) * 8);
    bdst[i] = 16384 + plane * 8192 + cg * 1024;
  }
  const int adst = (w * 2) * 1024;

  // --- fragment read constants ---
  const int lm = l & 15, kh = l >> 4;
  const int p0 = ((2 * kh) ^ (lm & 7)) * 16;
  const int p1 = ((2 * kh + 1) ^ (lm & 7)) * 16;
  const int bswz = (kh ^ ((lm >> 1) & 3)) * 16;
  int aoff[4], boff[2];
#pragma unroll
  for (int mf = 0; mf < 4; ++mf) aoff[mf] = (wr * 64 + mf * 16 + lm) * 128;
#pragma unroll
  for (int nf = 0; nf < 2; ++nf) boff[nf] = 16384 + (wc * 32 + nf * 16 + lm) * 64 + bswz;

  f32x4 acc_h[4][2], acc_m[4][2];
#pragma unroll
  for (int i = 0; i < 4; ++i)
#pragma unroll
    for (int j = 0; j < 2; ++j) {
      acc_h[i][j] = (f32x4){0.f, 0.f, 0.f, 0.f};
      acc_m[i][j] = (f32x4){0.f, 0.f, 0.f, 0.f};
    }

  auto STAGE = [&](int buf, int kt) {  // 4 gload_lds per wave
    const int k0 = kt * 32;
    char* base = lds + buf * 32768;
#pragma unroll
    for (int i = 0; i < 2; ++i) {
      int k = k0 + jA;
      int off = (k < 700) ? (arow[i] + k) : 0;  // pad: B plane is zero there
      gload16(x + off, base + adst + i * 1024);
    }
#pragma unroll
    for (int i = 0; i < 2; ++i)
      gload16(bsrc[i] + k0, base + bdst[i]);
  };

  STAGE(0, 0);
  __syncthreads();
  int buf = 0;
  for (int kt = 0; kt < 22; ++kt) {
    if (kt + 1 < 22) STAGE(buf ^ 1, kt + 1);
    const char* base = lds + buf * 32768;
    half8 b1[2], b2f[2];
#pragma unroll
    for (int nf = 0; nf < 2; ++nf) {
      const char* bb = base + boff[nf];
      b1[nf] = *(const half8*)(bb);
      b2f[nf] = *(const half8*)(bb + 8192);
    }
#pragma unroll
    for (int mf = 0; mf < 4; ++mf) {
      const char* ab = base + aoff[mf];
      float4 q0 = *(const float4*)(ab + p0);
      float4 q1 = *(const float4*)(ab + p1);
      half8 a1, a2;
      splitf16(q0, q1, a1, a2);
#pragma unroll
      for (int nf = 0; nf < 2; ++nf) {
        acc_h[mf][nf] = MFMA16F(a1, b1[nf], acc_h[mf][nf]);
        acc_m[mf][nf] = MFMA16F(a1, b2f[nf], acc_m[mf][nf]);
        acc_m[mf][nf] = MFMA16F(a2, b1[nf], acc_m[mf][nf]);
      }
    }
    __syncthreads();
    buf ^= 1;
  }

  // Bias (per fragment column)
  float bias[2];
#pragma unroll
  for (int nf = 0; nf < 2; ++nf) {
    int col = wc * 32 + nf * 16 + lm;
    bias[nf] = b_in[col] + b_rec[col];
  }

  // --- Scan overlay pointers ---
  float* XWs = (float*)lds;                 // [64][132]
  u64* smaskp = (u64*)(lds + 33792);        // [4][2]
  u64* fmaskp = (u64*)(lds + 33856);        // [4][16][2]
  float* tap = (float*)(lds + 34880);       // [4][16]
  float* m0p = (float*)(lds + 35136);       // [4][130]
  float* cap = (float*)(lds + 37216);       // [4][128]
  float* gp = (float*)(lds + 39264);        // [4][128]

  const int s = tid >> 7;       // sample within chunk (0..3)
  const int c = tid & 127;      // channel
  const int wv = (tid >> 6) & 1;
  const int lane = tid & 63;
  const float b2c = b2[c];
  const float bpc = b_p[c];

  for (int chunk = 0; chunk < 2; ++chunk) {
    __syncthreads();  // prior chunk / K-loop fully done with LDS
    if (tid < 8) smaskp[tid] = 0ull;
    if (wr == chunk) {
      // store this wave's acc rows (local rows 0..63 of the chunk)
      // C/D layout: col=lane&15, row=(lane>>4)*4+r (m89-verified)
#pragma unroll
      for (int nf = 0; nf < 2; ++nf) {
        int col = wc * 32 + nf * 16 + lm;
#pragma unroll
        for (int mf = 0; mf < 4; ++mf) {
          int rowl = mf * 16 + kh * 4;
#pragma unroll
          for (int r = 0; r < 4; ++r)
            XWs[(rowl + r) * 132 + col] =
                acc_h[mf][nf][r] * 0.000244140625f +
                acc_m[mf][nf][r] * 1.1920928955078125e-7f + bias[nf];
        }
      }
    }
    __syncthreads();

    const int n_glob = blk * 8 + chunk * 4 + s;
    float v1 = 0.f, v2 = 0.f, fsum = 0.f;

    // ---- phase 1: recurrent LIF scan (XW from LDS) ----
    for (int t = 0; t < 16; ++t) {
      float inp = XWs[(s * 16 + t) * 132 + c];
      u64 pm0 = smaskp[s * 2 + 0], pm1 = smaskp[s * 2 + 1];
      while (pm0) { int j = __builtin_ctzll(pm0); pm0 &= pm0 - 1; inp += WrT[j * 128 + c]; }
      while (pm1) { int j = __builtin_ctzll(pm1); pm1 &= pm1 - 1; inp += WrT[(64 + j) * 128 + c]; }
      v1 = v1 + (inp - v1) * 0.5f;          // decay_input=True, TAU=2
      bool s1 = (v1 - 1.0f) >= 0.f;
      v1 = s1 ? 0.f : v1;
      __syncthreads();                      // all reads of old smask done
      u64 bm = __ballot((int)s1);
      if (lane == 0) smaskp[s * 2 + wv] = bm;
      __syncthreads();
      float x2 = b2c;
      u64 q0 = smaskp[s * 2 + 0], q1 = smaskp[s * 2 + 1];
      while (q0) { int j = __builtin_ctzll(q0); q0 &= q0 - 1; x2 += W2T[j * 128 + c]; }
      while (q1) { int j = __builtin_ctzll(q1); q1 &= q1 - 1; x2 += W2T[(64 + j) * 128 + c]; }
      v2 = v2 + (x2 - v2) * 0.5f;
      bool f = (v2 - 1.0f) >= 0.f;
      v2 = f ? 0.f : v2;
      float ff = f ? 1.f : 0.f;
      features[(size_t)((t << 12) | n_glob) * 128 + c] = ff;
      fsum += ff;
      u64 fb = __ballot((int)f);
      if (lane == 0) fmaskp[(s * 16 + t) * 2 + wv] = fb;
    }

    // mean0 (exact: integer sums, pow2 divides)
    m0p[s * 130 + c + 1] = fsum * (1.f / 16.f);
    if (c == 0) { m0p[s * 130 + 0] = 0.f; m0p[s * 130 + 129] = 0.f; }
    __syncthreads();  // fmask + m0p complete

    // t_att: conv over T (SAME, width 3) + sigmoid
    if (c < 16) {
      float acc = 0.f;
#pragma unroll
      for (int j = 0; j < 3; ++j) {
        int tt = c - 1 + j;
        if (tt >= 0 && tt < 16) {
          float m = (float)(__popcll(fmaskp[(s * 16 + tt) * 2 + 0]) +
                            __popcll(fmaskp[(s * 16 + tt) * 2 + 1])) * (1.f / 128.f);
          acc += k_t[j] * m;
        }
      }
      tap[s * 16 + c] = 1.f / (1.f + expf(-acc));
    }
    // c_att: conv over C (SAME, width 3) + sigmoid
    {
      float acc = k_c[0] * m0p[s * 130 + c] + k_c[1] * m0p[s * 130 + c + 1] +
                  k_c[2] * m0p[s * 130 + c + 2];
      cap[s * 128 + c] = 1.f / (1.f + expf(-acc));
    }
    __syncthreads();

    // ---- phase 2: attended + LIF layer3 + spike-count ----
    float v3 = 0.f, ssum = 0.f;
    const float cac = cap[s * 128 + c];
    for (int t = 0; t < 16; ++t) {
      u64 m0 = fmaskp[(s * 16 + t) * 2 + 0], m1 = fmaskp[(s * 16 + t) * 2 + 1];
      float tat = tap[s * 16 + t];
      bool bit = ((wv ? m1 : m0) >> (c & 63)) & 1;
      float att = bit ? tat * cac : 0.f;    // feat in {0,1}: (feat*ta)*ca
      attended[(size_t)((t << 12) | n_glob) * 128 + c] = att;
      float h = bpc;
      while (m0) { int j = __builtin_ctzll(m0); m0 &= m0 - 1; h += (tat * cap[s * 128 + j]) * WpT[j * 128 + c]; }
      while (m1) { int j = __builtin_ctzll(m1); m1 &= m1 - 1; h += (tat * cap[s * 128 + 64 + j]) * WpT[(64 + j) * 128 + c]; }
      v3 = v3 + (h - v3) * 0.5f;
      bool sp = (v3 - 1.0f) >= 0.f;
      v3 = sp ? 0.f : v3;
      ssum += sp ? 1.f : 0.f;
    }
    gp[s * 128 + c] = ssum * (1.f / 16.f);
    __syncthreads();
    if (c < 20) {
      float acc = b_out[c];
      for (int j = 0; j < 128; ++j) acc += gp[s * 128 + j] * W_out[c * 128 + j];
      out0[n_glob * 20 + c] = acc;
    }
  }
}

// ---------------------------------------------------------------------------
extern "C" void kernel_launch(void* const* d_in, const int* in_sizes, int n_in,
                              void* d_out, int out_size, void* d_ws, size_t ws_size,
                              hipStream_t stream) {
  const float* x     = (const float*)d_in[0];
  const float* W_in  = (const float*)d_in[1];
  const float* b_in  = (const float*)d_in[2];
  const float* W_rec = (const float*)d_in[3];
  const float* b_rec = (const float*)d_in[4];
  const float* W2    = (const float*)d_in[5];
  const float* b2    = (const float*)d_in[6];
  const float* k_t   = (const float*)d_in[7];
  const float* k_c   = (const float*)d_in[8];
  const float* W_p   = (const float*)d_in[9];
  const float* b_p   = (const float*)d_in[10];
  const float* W_out = (const float*)d_in[11];
  const float* b_out = (const float*)d_in[12];

  float* out      = (float*)d_out;
  float* out0     = out;                        // [4096,20]
  float* features = out + 81920;                // [16,4096,128]
  float* attended = out + 81920 + 8388608;      // [16,4096,128]

  float* ws  = (float*)d_ws;
  float* WrT = ws;                  // 16384 f32
  float* W2T = ws + 16384;          // 16384 f32
  float* WpT = ws + 32768;          // 16384 f32
  ushort* F2 = (ushort*)(ws + 49152);  // 2 x 128 x 704 f16 = 360 KB

  hipLaunchKernelGGL(k_prep, dim3(544), dim3(256), 0, stream,
                     W_rec, W2, W_p, W_in, WrT, W2T, WpT, F2);
  hipLaunchKernelGGL(k_gemm_scan, dim3(512), dim3(512), 0, stream,
                     x, F2, b_in, b_rec, WrT, W2T, b2, WpT, b_p, W_out, b_out,
                     k_t, k_c, features, attended, out0);
}

// Round 10
// 78.597 us; speedup vs baseline: 1.2019x; 1.2019x over previous
//
#include <hip/hip_runtime.h>
#include <hip/hip_bf16.h>
#include <stdint.h>

// Problem constants: N=4096, T=16, D=700 (pad 704), C=128, NC=20
// Output layout (f32): out0 [4096,20] | features [16,4096,128] | attended [16,4096,128]

typedef __attribute__((ext_vector_type(8))) _Float16 half8;  // f16x8 MFMA frag
typedef __attribute__((ext_vector_type(4))) float f32x4;
typedef unsigned long long u64;

#define MFMA16F(a, b, c) __builtin_amdgcn_mfma_f32_16x16x32_f16(a, b, c, 0, 0, 0)

__device__ inline void gload16(const void* g, void* l) {
  __builtin_amdgcn_global_load_lds(
      (const __attribute__((address_space(1))) uint32_t*)g,
      (__attribute__((address_space(3))) uint32_t*)l, 16, 0, 0);
}

// ---------------------------------------------------------------------------
// f16 2-plane split with subnormal-avoiding scales:
//   a = h*2^-4 + l*2^-15 + ra,  |ra| <= 2^-24|a|   (RNE both planes)
// ---------------------------------------------------------------------------
__device__ inline void splitf16(float4 q0, float4 q1, half8& hh, half8& ll) {
  float f[8] = {q0.x, q0.y, q0.z, q0.w, q1.x, q1.y, q1.z, q1.w};
  _Float16 H[8], L[8];
#pragma unroll
  for (int j = 0; j < 8; ++j) {
    _Float16 h1 = (_Float16)(f[j] * 16.0f);          // RNE
    float r = fmaf((float)h1, -0.0625f, f[j]);       // exact residual
    L[j] = (_Float16)(r * 32768.0f);                 // 2^15, RNE
    H[j] = h1;
  }
  __builtin_memcpy(&hh, H, 16);
  __builtin_memcpy(&ll, L, 16);
}

// ---------------------------------------------------------------------------
// Prep: transpose WrT/W2T/WpT + split W_in into 2 f16 planes (k-pad 704)
//   b = p1*2^-8 + p2*2^-19 + rb, |rb| <= 2^-24|b|
// ---------------------------------------------------------------------------
__global__ void k_prep(const float* __restrict__ Wr, const float* __restrict__ W2,
                       const float* __restrict__ Wp, const float* __restrict__ Win,
                       float* __restrict__ WrT, float* __restrict__ W2T,
                       float* __restrict__ WpT, ushort* __restrict__ F2) {
  int idx = blockIdx.x * blockDim.x + threadIdx.x;
  if (idx < 3 * 16384) {
    int sel = idx >> 14;
    int r = idx & 16383;
    int j = r >> 7, c = r & 127;
    const float* src = (sel == 0) ? Wr : (sel == 1) ? W2 : Wp;
    float* dst = (sel == 0) ? WrT : (sel == 1) ? W2T : WpT;
    dst[r] = src[c * 128 + j];
  } else {
    int i2 = idx - 49152;
    if (i2 >= 128 * 704) return;
    int c = i2 / 704, d = i2 - c * 704;
    float w = (d < 700) ? Win[c * 700 + d] : 0.f;
    _Float16 b1 = (_Float16)(w * 256.0f);            // RNE, scale 2^8
    float r = fmaf((float)b1, -0.00390625f, w);      // exact residual
    _Float16 b2 = (_Float16)(r * 524288.0f);         // scale 2^19, RNE
    ushort u1, u2;
    __builtin_memcpy(&u1, &b1, 2);
    __builtin_memcpy(&u2, &b2, 2);
    F2[i2] = u1;
    F2[90112 + i2] = u2;
  }
}

// ---------------------------------------------------------------------------
// Fused GEMM + barrier-free scan. m = n*16+t: block owns 8 complete samples.
// GEMM (R7 structure): f16 2-plane 3-product MFMA, 128x128 tile, BK=32,
// 512 threads, wave grid 2(row-64)x4(col-32), dbuf 64KB -> 2 blocks/CU.
// Epilogue: acc -> LDS XWs[128][128] f32 with XOR swizzle col^=((row>>2)&3)<<3
// (store <=2-way free, read = lane permutation). Then WAVE-PER-SAMPLE scan:
// lane owns channels {lane, lane+64}; spike masks are wave-local ballots in
// registers -> ZERO block barriers in the scan (LDS ops wave-ordered).
// ---------------------------------------------------------------------------
__global__ __launch_bounds__(512, 4) void k_gemm_scan(
    const float* __restrict__ x, const ushort* __restrict__ F2,
    const float* __restrict__ b_in, const float* __restrict__ b_rec,
    const float* __restrict__ WrT, const float* __restrict__ W2T,
    const float* __restrict__ b2, const float* __restrict__ WpT,
    const float* __restrict__ b_p, const float* __restrict__ W_out,
    const float* __restrict__ b_out, const float* __restrict__ k_t,
    const float* __restrict__ k_c, float* __restrict__ features,
    float* __restrict__ attended, float* __restrict__ out0) {
  __shared__ __align__(16) char lds[81920];
  // GEMM: 2 bufs x 32KB @0.  Scan: XWs f32[128][128] @0 (64KB, swizzled),
  // per-sample scratch 2KB @65536: fmask u64[16][2] @0, ta f32[16] @256,
  // ca f32[128] @320, mean0/g f32[128] @832.

  const int tid = threadIdx.x;
  const int w = tid >> 6;      // 0..7
  const int l = tid & 63;
  const int blk = blockIdx.x;
  const int wr = w >> 2;       // 0..1  (row group of 64)
  const int wc = w & 3;        // 0..3  (col group of 32)

  // --- A staging: rows m = blk*128 + r contiguous in x. ---
  const int jA = (((l & 7) ^ (l >> 3)) * 4);  // chunk-XOR swizzled source k-off
  int arow[2];
#pragma unroll
  for (int i = 0; i < 2; ++i)
    arow[i] = (blk * 128 + (w * 2 + i) * 8 + (l >> 3)) * 700;
  // --- B staging: 2 planes x 8 col-groups, wave does 2. ---
  const ushort* bsrc[2];
  int bdst[2];
#pragma unroll
  for (int i = 0; i < 2; ++i) {
    int idx = w * 2 + i;
    int plane = idx >> 3, cg = idx & 7;
    int col = cg * 16 + (l >> 2);
    bsrc[i] = F2 + plane * 90112 + col * 704 + (((l & 3) ^ ((l >> 3) & 3)) * 8);
    bdst[i] = 16384 + plane * 8192 + cg * 1024;
  }
  const int adst = (w * 2) * 1024;

  // --- fragment read constants ---
  const int lm = l & 15, kh = l >> 4;
  const int p0 = ((2 * kh) ^ (lm & 7)) * 16;
  const int p1 = ((2 * kh + 1) ^ (lm & 7)) * 16;
  const int bswz = (kh ^ ((lm >> 1) & 3)) * 16;
  int aoff[4], boff[2];
#pragma unroll
  for (int mf = 0; mf < 4; ++mf) aoff[mf] = (wr * 64 + mf * 16 + lm) * 128;
#pragma unroll
  for (int nf = 0; nf < 2; ++nf) boff[nf] = 16384 + (wc * 32 + nf * 16 + lm) * 64 + bswz;

  f32x4 acc_h[4][2], acc_m[4][2];
#pragma unroll
  for (int i = 0; i < 4; ++i)
#pragma unroll
    for (int j = 0; j < 2; ++j) {
      acc_h[i][j] = (f32x4){0.f, 0.f, 0.f, 0.f};
      acc_m[i][j] = (f32x4){0.f, 0.f, 0.f, 0.f};
    }

  auto STAGE = [&](int buf, int kt) {  // 4 gload_lds per wave
    const int k0 = kt * 32;
    char* base = lds + buf * 32768;
#pragma unroll
    for (int i = 0; i < 2; ++i) {
      int k = k0 + jA;
      int off = (k < 700) ? (arow[i] + k) : 0;  // pad: B plane is zero there
      gload16(x + off, base + adst + i * 1024);
    }
#pragma unroll
    for (int i = 0; i < 2; ++i)
      gload16(bsrc[i] + k0, base + bdst[i]);
  };

  STAGE(0, 0);
  __syncthreads();
  int buf = 0;
  for (int kt = 0; kt < 22; ++kt) {
    if (kt + 1 < 22) STAGE(buf ^ 1, kt + 1);
    const char* base = lds + buf * 32768;
    half8 b1[2], b2f[2];
#pragma unroll
    for (int nf = 0; nf < 2; ++nf) {
      const char* bb = base + boff[nf];
      b1[nf] = *(const half8*)(bb);
      b2f[nf] = *(const half8*)(bb + 8192);
    }
#pragma unroll
    for (int mf = 0; mf < 4; ++mf) {
      const char* ab = base + aoff[mf];
      float4 q0 = *(const float4*)(ab + p0);
      float4 q1 = *(const float4*)(ab + p1);
      half8 a1, a2;
      splitf16(q0, q1, a1, a2);
#pragma unroll
      for (int nf = 0; nf < 2; ++nf) {
        acc_h[mf][nf] = MFMA16F(a1, b1[nf], acc_h[mf][nf]);
        acc_m[mf][nf] = MFMA16F(a1, b2f[nf], acc_m[mf][nf]);
        acc_m[mf][nf] = MFMA16F(a2, b1[nf], acc_m[mf][nf]);
      }
    }
    __syncthreads();
    buf ^= 1;
  }

  // --- Epilogue: acc -> XWs (swizzled). All K-loop LDS reads are behind the
  // final barrier, so staging buffers are dead and reusable now.
  float* XWs = (float*)lds;
#pragma unroll
  for (int nf = 0; nf < 2; ++nf) {
    int col = wc * 32 + nf * 16 + lm;
    float bias = b_in[col] + b_rec[col];
    int colx = col ^ (kh << 3);  // ((row>>2)&3)==kh for all 4 rows r
#pragma unroll
    for (int mf = 0; mf < 4; ++mf) {
      int rowl = wr * 64 + mf * 16 + kh * 4;
#pragma unroll
      for (int r = 0; r < 4; ++r)
        XWs[(rowl + r) * 128 + colx] =
            acc_h[mf][nf][r] * 0.000244140625f +
            acc_m[mf][nf][r] * 1.1920928955078125e-7f + bias;
    }
  }
  __syncthreads();  // the ONLY scan barrier: all XWs strips visible

  // ================= wave-per-sample scan (no block barriers) ==============
  const int s = w;                       // sample 0..7
  const int n_glob = blk * 8 + s;
  char* sc = lds + 65536 + s * 2048;
  u64* fmaskp = (u64*)sc;                // [16][2]
  float* tap = (float*)(sc + 256);       // [16]
  float* cap = (float*)(sc + 320);       // [128]
  float* gp = (float*)(sc + 832);        // [128] (mean0 temp, then g)

  const float b2a = b2[l], b2b = b2[l + 64];
  float v1a = 0.f, v1b = 0.f, v2a = 0.f, v2b = 0.f, fsa = 0.f, fsb = 0.f;
  u64 pm0 = 0ull, pm1 = 0ull;            // layer-1 spike masks (regs)

  for (int t = 0; t < 16; ++t) {
    const float* xrow = XWs + (s * 16 + t) * 128;
    const int key = ((t >> 2) & 3) << 3;
    float ia = xrow[l ^ key];
    float ib = xrow[(l + 64) ^ key];
    u64 q0 = pm0, q1 = pm1;
    while (q0) { int j = __builtin_ctzll(q0); q0 &= q0 - 1;
      ia += WrT[j * 128 + l]; ib += WrT[j * 128 + l + 64]; }
    while (q1) { int j = __builtin_ctzll(q1); q1 &= q1 - 1;
      ia += WrT[(64 + j) * 128 + l]; ib += WrT[(64 + j) * 128 + l + 64]; }
    v1a = v1a + (ia - v1a) * 0.5f;       // decay_input=True, TAU=2
    bool sa = (v1a - 1.0f) >= 0.f; v1a = sa ? 0.f : v1a;
    v1b = v1b + (ib - v1b) * 0.5f;
    bool sb = (v1b - 1.0f) >= 0.f; v1b = sb ? 0.f : v1b;
    pm0 = __ballot((int)sa);
    pm1 = __ballot((int)sb);
    float xa = b2a, xb = b2b;
    u64 r0 = pm0, r1 = pm1;
    while (r0) { int j = __builtin_ctzll(r0); r0 &= r0 - 1;
      xa += W2T[j * 128 + l]; xb += W2T[j * 128 + l + 64]; }
    while (r1) { int j = __builtin_ctzll(r1); r1 &= r1 - 1;
      xa += W2T[(64 + j) * 128 + l]; xb += W2T[(64 + j) * 128 + l + 64]; }
    v2a = v2a + (xa - v2a) * 0.5f;
    bool fa = (v2a - 1.0f) >= 0.f; v2a = fa ? 0.f : v2a;
    v2b = v2b + (xb - v2b) * 0.5f;
    bool fb = (v2b - 1.0f) >= 0.f; v2b = fb ? 0.f : v2b;
    float ffa = fa ? 1.f : 0.f, ffb = fb ? 1.f : 0.f;
    features[(size_t)((t << 12) | n_glob) * 128 + l] = ffa;
    features[(size_t)((t << 12) | n_glob) * 128 + l + 64] = ffb;
    fsa += ffa; fsb += ffb;
    u64 f0 = __ballot((int)fa), f1 = __ballot((int)fb);
    if (l == 0) { fmaskp[t * 2 + 0] = f0; fmaskp[t * 2 + 1] = f1; }
  }

  // mean0 into gp (temp), wave-ordered LDS
  gp[l] = fsa * (1.f / 16.f);
  gp[l + 64] = fsb * (1.f / 16.f);

  // t_att: conv over T (SAME, width 3) of channel-mean popcounts + sigmoid
  if (l < 16) {
    float acc = 0.f;
#pragma unroll
    for (int j = 0; j < 3; ++j) {
      int tt = l - 1 + j;
      if (tt >= 0 && tt < 16) {
        float m = (float)(__popcll(fmaskp[tt * 2 + 0]) +
                          __popcll(fmaskp[tt * 2 + 1])) * (1.f / 128.f);
        acc += k_t[j] * m;
      }
    }
    tap[l] = 1.f / (1.f + expf(-acc));
  }
  // c_att: conv over C (SAME, width 3) of mean0 + sigmoid (both channels)
  {
    float mm1 = (l == 0) ? 0.f : gp[l - 1];
    float acc = k_c[0] * mm1 + k_c[1] * gp[l] + k_c[2] * gp[l + 1];
    cap[l] = 1.f / (1.f + expf(-acc));
    float np1 = (l == 63) ? 0.f : gp[l + 65];
    float acc2 = k_c[0] * gp[l + 63] + k_c[1] * gp[l + 64] + k_c[2] * np1;
    cap[l + 64] = 1.f / (1.f + expf(-acc2));
  }

  // ---- phase 2: attended + LIF layer3 + spike-count (wave-local) ----
  const float bpa = b_p[l], bpb = b_p[l + 64];
  const float caa = cap[l], cab = cap[l + 64];
  float v3a = 0.f, v3b = 0.f, ssa = 0.f, ssb = 0.f;
  for (int t = 0; t < 16; ++t) {
    u64 m0 = fmaskp[t * 2 + 0], m1 = fmaskp[t * 2 + 1];
    float tat = tap[t];
    bool ba = (m0 >> l) & 1, bb = (m1 >> l) & 1;
    attended[(size_t)((t << 12) | n_glob) * 128 + l] = ba ? tat * caa : 0.f;
    attended[(size_t)((t << 12) | n_glob) * 128 + l + 64] = bb ? tat * cab : 0.f;
    float ha = bpa, hb = bpb;
    u64 q0 = m0, q1 = m1;
    while (q0) { int j = __builtin_ctzll(q0); q0 &= q0 - 1;
      float w_ = tat * cap[j];
      ha += w_ * WpT[j * 128 + l]; hb += w_ * WpT[j * 128 + l + 64]; }
    while (q1) { int j = __builtin_ctzll(q1); q1 &= q1 - 1;
      float w_ = tat * cap[64 + j];
      ha += w_ * WpT[(64 + j) * 128 + l]; hb += w_ * WpT[(64 + j) * 128 + l + 64]; }
    v3a = v3a + (ha - v3a) * 0.5f;
    bool sa = (v3a - 1.0f) >= 0.f; v3a = sa ? 0.f : v3a;
    ssa += sa ? 1.f : 0.f;
    v3b = v3b + (hb - v3b) * 0.5f;
    bool sb = (v3b - 1.0f) >= 0.f; v3b = sb ? 0.f : v3b;
    ssb += sb ? 1.f : 0.f;
  }
  gp[l] = ssa * (1.f / 16.f);      // overwrite mean0 temp (dead)
  gp[l + 64] = ssb * (1.f / 16.f);
  if (l < 20) {
    float acc = b_out[l];
    for (int j = 0; j < 128; ++j) acc += gp[j] * W_out[l * 128 + j];
    out0[n_glob * 20 + l] = acc;
  }
}

// ---------------------------------------------------------------------------
extern "C" void kernel_launch(void* const* d_in, const int* in_sizes, int n_in,
                              void* d_out, int out_size, void* d_ws, size_t ws_size,
                              hipStream_t stream) {
  const float* x     = (const float*)d_in[0];
  const float* W_in  = (const float*)d_in[1];
  const float* b_in  = (const float*)d_in[2];
  const float* W_rec = (const float*)d_in[3];
  const float* b_rec = (const float*)d_in[4];
  const float* W2    = (const float*)d_in[5];
  const float* b2    = (const float*)d_in[6];
  const float* k_t   = (const float*)d_in[7];
  const float* k_c   = (const float*)d_in[8];
  const float* W_p   = (const float*)d_in[9];
  const float* b_p   = (const float*)d_in[10];
  const float* W_out = (const float*)d_in[11];
  const float* b_out = (const float*)d_in[12];

  float* out      = (float*)d_out;
  float* out0     = out;                        // [4096,20]
  float* features = out + 81920;                // [16,4096,128]
  float* attended = out + 81920 + 8388608;      // [16,4096,128]

  float* ws  = (float*)d_ws;
  float* WrT = ws;                  // 16384 f32
  float* W2T = ws + 16384;          // 16384 f32
  float* WpT = ws + 32768;          // 16384 f32
  ushort* F2 = (ushort*)(ws + 49152);  // 2 x 128 x 704 f16 = 360 KB

  hipLaunchKernelGGL(k_prep, dim3(544), dim3(256), 0, stream,
                     W_rec, W2, W_p, W_in, WrT, W2T, WpT, F2);
  hipLaunchKernelGGL(k_gemm_scan, dim3(512), dim3(512), 0, stream,
                     x, F2, b_in, b_rec, WrT, W2T, b2, WpT, b_p, W_out, b_out,
                     k_t, k_c, features, attended, out0);
}

// Round 11
// 74.687 us; speedup vs baseline: 1.2649x; 1.0523x over previous
//
#include <hip/hip_runtime.h>
#include <hip/hip_bf16.h>
#include <stdint.h>

// Problem constants: N=4096, T=16, D=700 (pad 704), C=128, NC=20
// Output layout (f32): out0 [4096,20] | features [16,4096,128] | attended [16,4096,128]

typedef __attribute__((ext_vector_type(8))) _Float16 half8;  // f16x8 MFMA frag
typedef __attribute__((ext_vector_type(4))) float f32x4;
typedef unsigned long long u64;

#define MFMA16F(a, b, c) __builtin_amdgcn_mfma_f32_16x16x32_f16(a, b, c, 0, 0, 0)

__device__ inline void gload16(const void* g, void* l) {
  __builtin_amdgcn_global_load_lds(
      (const __attribute__((address_space(1))) uint32_t*)g,
      (__attribute__((address_space(3))) uint32_t*)l, 16, 0, 0);
}

// ---------------------------------------------------------------------------
// f16 2-plane split with subnormal-avoiding scales:
//   a = h*2^-4 + l*2^-15 + ra,  |ra| <= 2^-24|a|   (RNE both planes)
// ---------------------------------------------------------------------------
__device__ inline void splitf16(float4 q0, float4 q1, half8& hh, half8& ll) {
  float f[8] = {q0.x, q0.y, q0.z, q0.w, q1.x, q1.y, q1.z, q1.w};
  _Float16 H[8], L[8];
#pragma unroll
  for (int j = 0; j < 8; ++j) {
    _Float16 h1 = (_Float16)(f[j] * 16.0f);          // RNE
    float r = fmaf((float)h1, -0.0625f, f[j]);       // exact residual
    L[j] = (_Float16)(r * 32768.0f);                 // 2^15, RNE
    H[j] = h1;
  }
  __builtin_memcpy(&hh, H, 16);
  __builtin_memcpy(&ll, L, 16);
}

// ---------------------------------------------------------------------------
// Prep: transpose WrT/W2T/WpT + split W_in into 2 f16 planes (k-pad 704)
//   b = p1*2^-8 + p2*2^-19 + rb, |rb| <= 2^-24|b|
// ---------------------------------------------------------------------------
__global__ void k_prep(const float* __restrict__ Wr, const float* __restrict__ W2,
                       const float* __restrict__ Wp, const float* __restrict__ Win,
                       float* __restrict__ WrT, float* __restrict__ W2T,
                       float* __restrict__ WpT, ushort* __restrict__ F2) {
  int idx = blockIdx.x * blockDim.x + threadIdx.x;
  if (idx < 3 * 16384) {
    int sel = idx >> 14;
    int r = idx & 16383;
    int j = r >> 7, c = r & 127;
    const float* src = (sel == 0) ? Wr : (sel == 1) ? W2 : Wp;
    float* dst = (sel == 0) ? WrT : (sel == 1) ? W2T : WpT;
    dst[r] = src[c * 128 + j];
  } else {
    int i2 = idx - 49152;
    if (i2 >= 128 * 704) return;
    int c = i2 / 704, d = i2 - c * 704;
    float w = (d < 700) ? Win[c * 700 + d] : 0.f;
    _Float16 b1 = (_Float16)(w * 256.0f);            // RNE, scale 2^8
    float r = fmaf((float)b1, -0.00390625f, w);      // exact residual
    _Float16 b2 = (_Float16)(r * 524288.0f);         // scale 2^19, RNE
    ushort u1, u2;
    __builtin_memcpy(&u1, &b1, 2);
    __builtin_memcpy(&u2, &b2, 2);
    F2[i2] = u1;
    F2[90112 + i2] = u2;
  }
}

// ---------------------------------------------------------------------------
// Fused GEMM + scan, 4 desynced blocks/CU. Tile 64x128, 256 threads, 4 waves.
// Wave = 16 rows x 128 cols (mf=1, nf=8). m = n*16+t: wave owns ONE sample.
// A: DIRECT global->VGPR (per-lane frag: row=lm, k=8*kh..), prefetched 1 kt
// ahead — no LDS, no staging barrier dependency, split redundancy 1.
// B: LDS dbuf 32KB via gload16 (chunk-XOR swizzled source), 1 barrier/kt.
// Epilogue+scan: wave w's acc rows ARE sample w's XWs rows -> fully wave-
// local after the K-loop's own last barrier (zero extra barriers).
// ---------------------------------------------------------------------------
__global__ __launch_bounds__(256, 4) void k_gemm_scan(
    const float* __restrict__ x, const ushort* __restrict__ F2,
    const float* __restrict__ b_in, const float* __restrict__ b_rec,
    const float* __restrict__ WrT, const float* __restrict__ W2T,
    const float* __restrict__ b2, const float* __restrict__ WpT,
    const float* __restrict__ b_p, const float* __restrict__ W_out,
    const float* __restrict__ b_out, const float* __restrict__ k_t,
    const float* __restrict__ k_c, float* __restrict__ features,
    float* __restrict__ attended, float* __restrict__ out0) {
  __shared__ __align__(16) char lds[39424];
  // GEMM: B dbuf 2 x 16KB @0.  Scan overlay: XWs f32[64][130] @0 (33280 B),
  // per-sample scratch 1536B @33280+w*1536: fmask u64[16][2] @0, ta @256,
  // ca @320, mean0/g @832.

  const int tid = threadIdx.x;
  const int w = tid >> 6;      // wave 0..3 = 16-row group = sample
  const int l = tid & 63;
  const int blk = blockIdx.x;
  const int lm = l & 15, kh = l >> 4;

  // --- A: direct per-lane loads; rows m = blk*64 + w*16 + lm contiguous in x.
  const float* xr = x + (size_t)(blk * 64 + w * 16 + lm) * 700;

  // --- B staging: 16 gload16/block-kt (2 planes x 8 col-groups), wave does 4.
  const ushort* bsrc[4];
  int bdst[4];
#pragma unroll
  for (int i = 0; i < 4; ++i) {
    int idx = w * 4 + i;
    int plane = idx >> 3, cg = idx & 7;
    int col = cg * 16 + (l >> 2);
    bsrc[i] = F2 + plane * 90112 + col * 704 + (((l & 3) ^ ((l >> 3) & 3)) * 8);
    bdst[i] = plane * 8192 + cg * 1024;
  }
  const int bkey = (lm >> 1) & 3;
  const int brd = lm * 64 + ((kh ^ bkey) * 16);

  f32x4 acc_h[8], acc_m[8];
#pragma unroll
  for (int j = 0; j < 8; ++j) {
    acc_h[j] = (f32x4){0.f, 0.f, 0.f, 0.f};
    acc_m[j] = (f32x4){0.f, 0.f, 0.f, 0.f};
  }

  auto STAGE = [&](int buf, int kt) {  // 4 gload_lds per wave
    const int k0 = kt * 32;
#pragma unroll
    for (int i = 0; i < 4; ++i)
      gload16(bsrc[i] + k0, lds + buf * 16384 + bdst[i]);
  };
  auto LOADA = [&](int kt, float4& q0, float4& q1) {
    const int k0 = kt * 32 + kh * 8;
    q0 = *(const float4*)(xr + k0);
    if (kt == 21 && kh == 3)
      q1 = make_float4(0.f, 0.f, 0.f, 0.f);  // k 700..703: B-pad is zero
    else
      q1 = *(const float4*)(xr + k0 + 4);
  };

  STAGE(0, 0);
  float4 qa, qb;
  LOADA(0, qa, qb);
  __syncthreads();
  int buf = 0;
  for (int kt = 0; kt < 22; ++kt) {
    float4 na = {}, nb = {};
    if (kt < 21) {
      STAGE(buf ^ 1, kt + 1);
      LOADA(kt + 1, na, nb);
    }
    half8 a1, a2;
    splitf16(qa, qb, a1, a2);
    const char* bb0 = lds + buf * 16384 + brd;
#pragma unroll
    for (int nf = 0; nf < 8; ++nf) {
      const char* bb = bb0 + nf * 1024;
      half8 b1 = *(const half8*)(bb);
      half8 b2f = *(const half8*)(bb + 8192);
      acc_h[nf] = MFMA16F(a1, b1, acc_h[nf]);
      acc_m[nf] = MFMA16F(a1, b2f, acc_m[nf]);
      acc_m[nf] = MFMA16F(a2, b1, acc_m[nf]);
    }
    __syncthreads();   // buf consumed by all waves; next-kt B landed (vmcnt drain)
    qa = na; qb = nb;
    buf ^= 1;
  }

  // --- Epilogue (wave-local): acc -> XWs rows w*16.. (stride 130: 2-way banks)
  float* XWs = (float*)lds;
#pragma unroll
  for (int nf = 0; nf < 8; ++nf) {
    const int col = nf * 16 + lm;
    const float bias = b_in[col] + b_rec[col];
    const int rowb = w * 16 + kh * 4;
#pragma unroll
    for (int r = 0; r < 4; ++r)
      XWs[(rowb + r) * 130 + col] =
          acc_h[nf][r] * 0.000244140625f +
          acc_m[nf][r] * 1.1920928955078125e-7f + bias;
  }

  // ================= wave-per-sample scan (no barriers at all) =============
  const int n_glob = blk * 4 + w;
  char* sc = lds + 33280 + w * 1536;
  u64* fmaskp = (u64*)sc;                // [16][2]
  float* tap = (float*)(sc + 256);       // [16]
  float* cap = (float*)(sc + 320);       // [128]
  float* gp = (float*)(sc + 832);        // [128] (mean0 temp, then g)

  const float b2a = b2[l], b2b = b2[l + 64];
  float v1a = 0.f, v1b = 0.f, v2a = 0.f, v2b = 0.f, fsa = 0.f, fsb = 0.f;
  u64 pm0 = 0ull, pm1 = 0ull;            // layer-1 spike masks (regs)

  for (int t = 0; t < 16; ++t) {
    const float* xrow = XWs + (w * 16 + t) * 130;
    float ia = xrow[l];
    float ib = xrow[l + 64];
    u64 q0 = pm0, q1 = pm1;
    while (q0) { int j = __builtin_ctzll(q0); q0 &= q0 - 1;
      ia += WrT[j * 128 + l]; ib += WrT[j * 128 + l + 64]; }
    while (q1) { int j = __builtin_ctzll(q1); q1 &= q1 - 1;
      ia += WrT[(64 + j) * 128 + l]; ib += WrT[(64 + j) * 128 + l + 64]; }
    v1a = v1a + (ia - v1a) * 0.5f;       // decay_input=True, TAU=2
    bool sa = (v1a - 1.0f) >= 0.f; v1a = sa ? 0.f : v1a;
    v1b = v1b + (ib - v1b) * 0.5f;
    bool sb = (v1b - 1.0f) >= 0.f; v1b = sb ? 0.f : v1b;
    pm0 = __ballot((int)sa);
    pm1 = __ballot((int)sb);
    float xa = b2a, xb = b2b;
    u64 r0 = pm0, r1 = pm1;
    while (r0) { int j = __builtin_ctzll(r0); r0 &= r0 - 1;
      xa += W2T[j * 128 + l]; xb += W2T[j * 128 + l + 64]; }
    while (r1) { int j = __builtin_ctzll(r1); r1 &= r1 - 1;
      xa += W2T[(64 + j) * 128 + l]; xb += W2T[(64 + j) * 128 + l + 64]; }
    v2a = v2a + (xa - v2a) * 0.5f;
    bool fa = (v2a - 1.0f) >= 0.f; v2a = fa ? 0.f : v2a;
    v2b = v2b + (xb - v2b) * 0.5f;
    bool fb = (v2b - 1.0f) >= 0.f; v2b = fb ? 0.f : v2b;
    float ffa = fa ? 1.f : 0.f, ffb = fb ? 1.f : 0.f;
    features[(size_t)((t << 12) | n_glob) * 128 + l] = ffa;
    features[(size_t)((t << 12) | n_glob) * 128 + l + 64] = ffb;
    fsa += ffa; fsb += ffb;
    u64 f0 = __ballot((int)fa), f1 = __ballot((int)fb);
    if (l == 0) { fmaskp[t * 2 + 0] = f0; fmaskp[t * 2 + 1] = f1; }
  }

  // mean0 into gp (temp), wave-ordered LDS
  gp[l] = fsa * (1.f / 16.f);
  gp[l + 64] = fsb * (1.f / 16.f);

  // t_att: conv over T (SAME, width 3) of channel-mean popcounts + sigmoid
  if (l < 16) {
    float acc = 0.f;
#pragma unroll
    for (int j = 0; j < 3; ++j) {
      int tt = l - 1 + j;
      if (tt >= 0 && tt < 16) {
        float m = (float)(__popcll(fmaskp[tt * 2 + 0]) +
                          __popcll(fmaskp[tt * 2 + 1])) * (1.f / 128.f);
        acc += k_t[j] * m;
      }
    }
    tap[l] = 1.f / (1.f + expf(-acc));
  }
  // c_att: conv over C (SAME, width 3) of mean0 + sigmoid (both channels)
  {
    float mm1 = (l == 0) ? 0.f : gp[l - 1];
    float acc = k_c[0] * mm1 + k_c[1] * gp[l] + k_c[2] * gp[l + 1];
    cap[l] = 1.f / (1.f + expf(-acc));
    float np1 = (l == 63) ? 0.f : gp[l + 65];
    float acc2 = k_c[0] * gp[l + 63] + k_c[1] * gp[l + 64] + k_c[2] * np1;
    cap[l + 64] = 1.f / (1.f + expf(-acc2));
  }

  // ---- phase 2: attended + LIF layer3 + spike-count (wave-local) ----
  const float bpa = b_p[l], bpb = b_p[l + 64];
  const float caa = cap[l], cab = cap[l + 64];
  float v3a = 0.f, v3b = 0.f, ssa = 0.f, ssb = 0.f;
  for (int t = 0; t < 16; ++t) {
    u64 m0 = fmaskp[t * 2 + 0], m1 = fmaskp[t * 2 + 1];
    float tat = tap[t];
    bool ba = (m0 >> l) & 1, bb = (m1 >> l) & 1;
    attended[(size_t)((t << 12) | n_glob) * 128 + l] = ba ? tat * caa : 0.f;
    attended[(size_t)((t << 12) | n_glob) * 128 + l + 64] = bb ? tat * cab : 0.f;
    float ha = bpa, hb = bpb;
    u64 q0 = m0, q1 = m1;
    while (q0) { int j = __builtin_ctzll(q0); q0 &= q0 - 1;
      float w_ = tat * cap[j];
      ha += w_ * WpT[j * 128 + l]; hb += w_ * WpT[j * 128 + l + 64]; }
    while (q1) { int j = __builtin_ctzll(q1); q1 &= q1 - 1;
      float w_ = tat * cap[64 + j];
      ha += w_ * WpT[(64 + j) * 128 + l]; hb += w_ * WpT[(64 + j) * 128 + l + 64]; }
    v3a = v3a + (ha - v3a) * 0.5f;
    bool sa = (v3a - 1.0f) >= 0.f; v3a = sa ? 0.f : v3a;
    ssa += sa ? 1.f : 0.f;
    v3b = v3b + (hb - v3b) * 0.5f;
    bool sb = (v3b - 1.0f) >= 0.f; v3b = sb ? 0.f : v3b;
    ssb += sb ? 1.f : 0.f;
  }
  gp[l] = ssa * (1.f / 16.f);      // overwrite mean0 temp (dead)
  gp[l + 64] = ssb * (1.f / 16.f);
  if (l < 20) {
    float acc = b_out[l];
    for (int j = 0; j < 128; ++j) acc += gp[j] * W_out[l * 128 + j];
    out0[n_glob * 20 + l] = acc;
  }
}

// ---------------------------------------------------------------------------
extern "C" void kernel_launch(void* const* d_in, const int* in_sizes, int n_in,
                              void* d_out, int out_size, void* d_ws, size_t ws_size,
                              hipStream_t stream) {
  const float* x     = (const float*)d_in[0];
  const float* W_in  = (const float*)d_in[1];
  const float* b_in  = (const float*)d_in[2];
  const float* W_rec = (const float*)d_in[3];
  const float* b_rec = (const float*)d_in[4];
  const float* W2    = (const float*)d_in[5];
  const float* b2    = (const float*)d_in[6];
  const float* k_t   = (const float*)d_in[7];
  const float* k_c   = (const float*)d_in[8];
  const float* W_p   = (const float*)d_in[9];
  const float* b_p   = (const float*)d_in[10];
  const float* W_out = (const float*)d_in[11];
  const float* b_out = (const float*)d_in[12];

  float* out      = (float*)d_out;
  float* out0     = out;                        // [4096,20]
  float* features = out + 81920;                // [16,4096,128]
  float* attended = out + 81920 + 8388608;      // [16,4096,128]

  float* ws  = (float*)d_ws;
  float* WrT = ws;                  // 16384 f32
  float* W2T = ws + 16384;          // 16384 f32
  float* WpT = ws + 32768;          // 16384 f32
  ushort* F2 = (ushort*)(ws + 49152);  // 2 x 128 x 704 f16 = 360 KB

  hipLaunchKernelGGL(k_prep, dim3(544), dim3(256), 0, stream,
                     W_rec, W2, W_p, W_in, WrT, W2T, WpT, F2);
  hipLaunchKernelGGL(k_gemm_scan, dim3(1024), dim3(256), 0, stream,
                     x, F2, b_in, b_rec, WrT, W2T, b2, WpT, b_p, W_out, b_out,
                     k_t, k_c, features, attended, out0);
}